// Round 1
// baseline (501.375 us; speedup 1.0000x reference)
//
#include <hip/hip_runtime.h>
#include <math.h>

#define BB 2
#define CC 512
#define HH 30
#define WW 40
#define KK 64
#define NPIX (HH*WW)
#define HP 27
#define WP 37
#define NP (HP*WP)
#define LEPS 1e-12f

// ---------------------------------------------------------------------------
// Kernel 1: per-(b,h) row: channel L2-norm, xn store, logits (K=64) + softmax.
// ---------------------------------------------------------------------------
__global__ __launch_bounds__(512) void k_norm_soft(
    const float* __restrict__ x, const float* __restrict__ convw,
    float* __restrict__ xn, float* __restrict__ soft)
{
  const int h = blockIdx.x, b = blockIdx.y;
  const int t = threadIdx.x;
  __shared__ float xc[64][41];       // normalized channel chunk [c][w]
  __shared__ float cw[64][65];       // conv_w chunk [k][c]
  __shared__ float Lb[KK][WW + 1];   // logits
  __shared__ float psum[12][WW];
  __shared__ float invn[WW];
  __shared__ float mx[WW], Zs[WW];

  const size_t xbase = (size_t)b * CC * NPIX + (size_t)h * WW;

  // Phase A: per-pixel sum of squares over channels
  if (t < 480) {
    const int w = t % 40, part = t / 40;   // 12 c-partitions
    float s = 0.f;
    for (int c = part; c < CC; c += 12) {
      const float v = x[xbase + (size_t)c * NPIX + w];
      s = fmaf(v, v, s);
    }
    psum[part][w] = s;
  }
  __syncthreads();
  if (t < 40) {
    float s = 0.f;
    #pragma unroll
    for (int p = 0; p < 12; ++p) s += psum[p][t];
    invn[t] = 1.f / fmaxf(sqrtf(s), LEPS);
  }
  __syncthreads();

  // Phase B: chunked normalize + logits accumulation
  const int k = t & 63, wp = t >> 6;       // 64 k x 8 w-parts
  float acc[5] = {0.f, 0.f, 0.f, 0.f, 0.f};
  for (int cb = 0; cb < CC; cb += 64) {
    #pragma unroll
    for (int n = 0; n < 5; ++n) {
      const int idx = t + 512 * n;         // 0..2559 -> 64c x 40w
      const int c = idx / 40, w = idx % 40;
      const float v = x[xbase + (size_t)(cb + c) * NPIX + w] * invn[w];
      xc[c][w] = v;
      xn[xbase + (size_t)(cb + c) * NPIX + w] = v;
    }
    #pragma unroll
    for (int n = 0; n < 8; ++n) {
      const int idx = t + 512 * n;         // 0..4095 -> 64k x 64c
      const int kk2 = idx >> 6, c2 = idx & 63;
      cw[kk2][c2] = convw[(size_t)kk2 * CC + cb + c2];
    }
    __syncthreads();
    #pragma unroll 1
    for (int c = 0; c < 64; ++c) {
      const float cv = cw[k][c];
      #pragma unroll
      for (int n = 0; n < 5; ++n)
        acc[n] = fmaf(cv, xc[c][wp + 8 * n], acc[n]);
    }
    __syncthreads();
  }
  #pragma unroll
  for (int n = 0; n < 5; ++n) Lb[k][wp + 8 * n] = acc[n];
  __syncthreads();
  if (t < 40) {
    float m = -1e30f;
    for (int kk2 = 0; kk2 < KK; ++kk2) m = fmaxf(m, Lb[kk2][t]);
    float Z = 0.f;
    for (int kk2 = 0; kk2 < KK; ++kk2) Z += expf(Lb[kk2][t] - m);
    mx[t] = m; Zs[t] = Z;
  }
  __syncthreads();
  const size_t sbase = (size_t)b * KK * NPIX + (size_t)h * WW;
  #pragma unroll
  for (int n = 0; n < 5; ++n) {
    const int idx = t + 512 * n;           // 0..2559 -> 64k x 40w
    const int kk2 = idx / 40, w = idx % 40;
    soft[sbase + (size_t)kk2 * NPIX + w] = expf(Lb[kk2][w] - mx[w]) / Zs[w];
  }
}

// ---------------------------------------------------------------------------
// Kernel G: per-(b,k): vlad_global row = sum_p soft*xn - cent*sum(soft),
//           normalized over c; written to ws.ghat.
// ---------------------------------------------------------------------------
__global__ __launch_bounds__(256) void k_global(
    const float* __restrict__ xn, const float* __restrict__ soft,
    const float* __restrict__ cent, float* __restrict__ ghat)
{
  const int k = blockIdx.x, b = blockIdx.y, t = threadIdx.x;
  __shared__ float sb[NPIX];
  __shared__ float red[256];
  const float* srow = soft + ((size_t)b * KK + k) * NPIX;
  for (int i2 = t; i2 < NPIX; i2 += 256) sb[i2] = srow[i2];
  __syncthreads();
  float p = 0.f;
  for (int i2 = t; i2 < NPIX; i2 += 256) p += sb[i2];
  red[t] = p;
  __syncthreads();
  for (int s = 128; s > 0; s >>= 1) { if (t < s) red[t] += red[t + s]; __syncthreads(); }
  const float Sg = red[0];
  __syncthreads();

  const int c0 = t, c1 = t + 256;
  const float* x0 = xn + ((size_t)b * CC + c0) * NPIX;
  const float* x1 = xn + ((size_t)b * CC + c1) * NPIX;
  float a0 = 0.f, a1 = 0.f;
  for (int p4 = 0; p4 < NPIX; p4 += 4) {
    const float4 s4 = *(const float4*)&sb[p4];
    const float4 v0 = *(const float4*)(x0 + p4);
    const float4 v1 = *(const float4*)(x1 + p4);
    a0 = fmaf(s4.x, v0.x, a0); a0 = fmaf(s4.y, v0.y, a0);
    a0 = fmaf(s4.z, v0.z, a0); a0 = fmaf(s4.w, v0.w, a0);
    a1 = fmaf(s4.x, v1.x, a1); a1 = fmaf(s4.y, v1.y, a1);
    a1 = fmaf(s4.z, v1.z, a1); a1 = fmaf(s4.w, v1.w, a1);
  }
  const float g0 = a0 - cent[(size_t)k * CC + c0] * Sg;
  const float g1 = a1 - cent[(size_t)k * CC + c1] * Sg;
  red[t] = g0 * g0 + g1 * g1;
  __syncthreads();
  for (int s = 128; s > 0; s >>= 1) { if (t < s) red[t] += red[t + s]; __syncthreads(); }
  const float inv = 1.f / fmaxf(sqrtf(red[0]), LEPS);
  float* gr = ghat + ((size_t)b * KK + k) * CC;
  gr[c0] = g0 * inv; gr[c1] = g1 * inv;
}

// Kernel G2: per-b second L2 norm over all K*C, write final vlad_global.
__global__ __launch_bounds__(256) void k_global2(
    const float* __restrict__ ghat, float* __restrict__ outg)
{
  const int b = blockIdx.x, t = threadIdx.x;
  __shared__ float red[256];
  const float* gb = ghat + (size_t)b * KK * CC;
  float p = 0.f;
  for (int i2 = t; i2 < KK * CC; i2 += 256) { const float v = gb[i2]; p = fmaf(v, v, p); }
  red[t] = p;
  __syncthreads();
  for (int s = 128; s > 0; s >>= 1) { if (t < s) red[t] += red[t + s]; __syncthreads(); }
  const float inv = 1.f / fmaxf(sqrtf(red[0]), LEPS);
  for (int i2 = t; i2 < KK * CC; i2 += 256)
    outg[(size_t)b * KK * CC + i2] = gb[i2] * inv;
}

// ---------------------------------------------------------------------------
// Kernel L: per (b, k-group-of-4, output row i). raw = 16*box computed from a
// transposed xn slab in LDS with an 8c x 4k register tile.
// PHASE 0: accumulate sum_c raw^2 -> ws.ssq ; PHASE 1: scale by fs and write.
// ---------------------------------------------------------------------------
template<int PHASE>
__global__ __launch_bounds__(320) void k_local(
    const float* __restrict__ xn, const float* __restrict__ soft,
    const float* __restrict__ cent, float* __restrict__ ssq,
    const float* __restrict__ fs, float* __restrict__ out)
{
  const int i = blockIdx.x;            // output row, 0..26
  const int k0 = blockIdx.y * 4;       // k group
  const int b = blockIdx.z;
  const int t = threadIdx.x;           // 0..319

  __shared__ float soft_l[160][4];     // [px][k]  (px = 4 rows x 40 cols)
  __shared__ float S_l[4][40];         // patch sums of soft
  __shared__ float cent_l[4][CC];
  __shared__ float xn_l[160][68];      // [px][c]  pad 68 -> conflict-free b128
  __shared__ float aux[4][40];         // fs tile (PHASE 1)
  __shared__ float red[1280];          // ssq reduction (PHASE 0)

  #pragma unroll
  for (int n = 0; n < 2; ++n) {
    const int idx = t + 320 * n;       // 0..639
    const int kk = idx / 160, px = idx % 160;
    const int r = px / 40, col = px % 40;
    soft_l[px][kk] = soft[((size_t)(b * KK + k0 + kk)) * NPIX + (size_t)(i + r) * WW + col];
  }
  for (int idx = t; idx < 4 * CC; idx += 320)
    cent_l[idx >> 9][idx & 511] = cent[(size_t)(k0 + (idx >> 9)) * CC + (idx & 511)];
  if (PHASE == 1 && t < 160) {
    const int kk = t / 40, j = t % 40;
    aux[kk][j] = (j < WP) ? fs[((size_t)(b * KK + k0 + kk)) * NP + (size_t)i * WP + j] : 0.f;
  }
  __syncthreads();
  if (t < 160) {
    const int kk = t / 40, j = t % 40;
    float s = 0.f;
    if (j < WP) {
      #pragma unroll
      for (int r = 0; r < 4; ++r)
        #pragma unroll
        for (int dx = 0; dx < 4; ++dx)
          s += soft_l[r * 40 + j + dx][kk];
    }
    S_l[kk][j] = s;
  }
  __syncthreads();

  const int c8 = t / 40, j = t % 40;   // c8: 0..7, j: 0..39 (j>=37 idle)
  float ssqp[4] = {0.f, 0.f, 0.f, 0.f};

  for (int ch = 0; ch < 8; ++ch) {
    const int cb = ch * 64;
    // stage xn chunk transposed: [px][c]
    #pragma unroll
    for (int n = 0; n < 8; ++n) {
      const int idx4 = t + 320 * n;    // 0..2559 -> 64c x 40 quads
      const int c = idx4 / 40, q = idx4 % 40;
      const int r = q / 10, colq = q % 10;
      const float4 v = *(const float4*)(xn + ((size_t)(b * CC + cb + c)) * NPIX
                                        + (size_t)(i + r) * WW + colq * 4);
      const int px = r * 40 + colq * 4;
      xn_l[px + 0][c] = v.x; xn_l[px + 1][c] = v.y;
      xn_l[px + 2][c] = v.z; xn_l[px + 3][c] = v.w;
    }
    __syncthreads();
    if (j < WP) {
      float a[8][4];
      #pragma unroll
      for (int cc = 0; cc < 8; ++cc)
        #pragma unroll
        for (int kk = 0; kk < 4; ++kk) a[cc][kk] = 0.f;
      #pragma unroll
      for (int r = 0; r < 4; ++r) {
        #pragma unroll
        for (int dx = 0; dx < 4; ++dx) {
          const int px = r * 40 + j + dx;
          const float4 s4  = *(const float4*)&soft_l[px][0];
          const float4 xa  = *(const float4*)&xn_l[px][c8 * 8];
          const float4 xb4 = *(const float4*)&xn_l[px][c8 * 8 + 4];
          const float xv[8] = {xa.x, xa.y, xa.z, xa.w, xb4.x, xb4.y, xb4.z, xb4.w};
          const float sv[4] = {s4.x, s4.y, s4.z, s4.w};
          #pragma unroll
          for (int cc = 0; cc < 8; ++cc)
            #pragma unroll
            for (int kk = 0; kk < 4; ++kk)
              a[cc][kk] = fmaf(xv[cc], sv[kk], a[cc][kk]);
        }
      }
      #pragma unroll
      for (int kk = 0; kk < 4; ++kk) {
        const float Sv = S_l[kk][j];
        const float fv = (PHASE == 1) ? aux[kk][j] : 0.f;
        #pragma unroll
        for (int cc = 0; cc < 8; ++cc) {
          const int c = cb + c8 * 8 + cc;
          const float raw = fmaf(-cent_l[kk][c], Sv, a[cc][kk]);
          if (PHASE == 0)
            ssqp[kk] = fmaf(raw, raw, ssqp[kk]);
          else
            out[((size_t)((b * KK + k0 + kk) * CC + c)) * NP + (size_t)i * WP + j] = raw * fv;
        }
      }
    }
    __syncthreads();
  }
  if (PHASE == 0) {
    #pragma unroll
    for (int kk = 0; kk < 4; ++kk) red[(c8 * 4 + kk) * 40 + j] = ssqp[kk];
    __syncthreads();
    if (t < 160) {
      const int kk = t / 40, jj = t % 40;
      if (jj < WP) {
        float s = 0.f;
        #pragma unroll
        for (int g = 0; g < 8; ++g) s += red[(g * 4 + kk) * 40 + jj];
        ssq[((size_t)(b * KK + k0 + kk)) * NP + (size_t)i * WP + jj] = s;
      }
    }
  }
}

// ---------------------------------------------------------------------------
// Kernel NF: exact per-(b,k,p) final scale: 1/16 * 1/max(norm_k,eps) * 1/max(norm2,eps)
// where norm_k = sqrt(ssq_raw)/16 and norm2 is the honest cross-k second norm.
// ---------------------------------------------------------------------------
__global__ __launch_bounds__(256) void k_nf(
    const float* __restrict__ ssq, float* __restrict__ fs)
{
  const int b = blockIdx.y;
  const int p = blockIdx.x * 256 + threadIdx.x;
  if (p >= NP) return;
  float n2s = 0.f;
  for (int k = 0; k < KK; ++k) {
    const float sr = ssq[((size_t)(b * KK + k)) * NP + p];
    const float iv = 1.f / fmaxf(sqrtf(sr) * 0.0625f, LEPS);
    n2s += sr * (1.f / 256.f) * iv * iv;
  }
  const float inv2 = 1.f / fmaxf(sqrtf(n2s), LEPS);
  for (int k = 0; k < KK; ++k) {
    const float sr = ssq[((size_t)(b * KK + k)) * NP + p];
    const float iv = 1.f / fmaxf(sqrtf(sr) * 0.0625f, LEPS);
    fs[((size_t)(b * KK + k)) * NP + p] = 0.0625f * iv * inv2;
  }
}

// ---------------------------------------------------------------------------
extern "C" void kernel_launch(void* const* d_in, const int* in_sizes, int n_in,
                              void* d_out, int out_size, void* d_ws, size_t ws_size,
                              hipStream_t stream)
{
  const float* x     = (const float*)d_in[0];
  const float* convw = (const float*)d_in[1];
  const float* cent  = (const float*)d_in[2];
  float* out = (float*)d_out;
  float* ws  = (float*)d_ws;

  float* xn   = ws;                                  // B*C*NPIX
  float* soft = xn   + (size_t)BB * CC * NPIX;       // B*K*NPIX
  float* ssq  = soft + (size_t)BB * KK * NPIX;       // B*K*NP
  float* fs   = ssq  + (size_t)BB * KK * NP;         // B*K*NP
  float* ghat = fs   + (size_t)BB * KK * NP;         // B*K*C

  k_norm_soft<<<dim3(HH, BB), 512, 0, stream>>>(x, convw, xn, soft);
  k_global<<<dim3(KK, BB), 256, 0, stream>>>(xn, soft, cent, ghat);
  k_global2<<<dim3(BB), 256, 0, stream>>>(ghat, out + (size_t)BB * KK * CC * NP);
  k_local<0><<<dim3(HP, KK / 4, BB), 320, 0, stream>>>(xn, soft, cent, ssq, fs, out);
  k_nf<<<dim3((NP + 255) / 256, BB), 256, 0, stream>>>(ssq, fs);
  k_local<1><<<dim3(HP, KK / 4, BB), 320, 0, stream>>>(xn, soft, cent, ssq, fs, out);
}